// Round 2
// baseline (658.750 us; speedup 1.0000x reference)
//
#include <hip/hip_runtime.h>
#include <stdint.h>

typedef int v4i  __attribute__((ext_vector_type(4)));
typedef int v16i __attribute__((ext_vector_type(16)));

// async global->LDS, 16 B per lane; LDS dest must be wave-uniform base +
// lane*16 (contiguous 1024 B per wave).
__device__ __forceinline__ void async_load16(const void* g, void* l) {
    auto gp = (const __attribute__((address_space(1))) unsigned int*)(uintptr_t)g;
    auto lp = (__attribute__((address_space(3))) unsigned int*)(unsigned int)(uintptr_t)l;
    __builtin_amdgcn_global_load_lds(gp, lp, 16, 0, 0);
}

// ws layout: bits[0..1] = absmax bit patterns (x,w); sc[0]=s_x sc[1]=s_w sc[2]=1/(s_x*s_w)
__global__ void k_init(unsigned* bits) {
    if (threadIdx.x < 2) bits[threadIdx.x] = 0u;
}

// fused absmax: blocks [0,NBX) -> x, [NBX,NBX+NBW) -> w
__global__ void k_absmax(const float4* __restrict__ x, int n4x, int nbx,
                         const float4* __restrict__ w, int n4w, int nbw,
                         unsigned* __restrict__ bits) {
    const float4* in;
    int n4, b, nb;
    unsigned* ob;
    if ((int)blockIdx.x < nbx) { in = x; n4 = n4x; b = blockIdx.x; nb = nbx; ob = bits; }
    else { in = w; n4 = n4w; b = blockIdx.x - nbx; nb = nbw; ob = bits + 1; }
    float m0 = 0.f, m1 = 0.f;
    int stride = nb * blockDim.x * 2;
    for (int i = b * blockDim.x * 2 + threadIdx.x; i < n4; i += stride) {
        float4 v = in[i];
        m0 = fmaxf(m0, fmaxf(fmaxf(fabsf(v.x), fabsf(v.y)),
                             fmaxf(fabsf(v.z), fabsf(v.w))));
        int j = i + blockDim.x;
        if (j < n4) {
            float4 u = in[j];
            m1 = fmaxf(m1, fmaxf(fmaxf(fabsf(u.x), fabsf(u.y)),
                                 fmaxf(fabsf(u.z), fabsf(u.w))));
        }
    }
    float m = fmaxf(m0, m1);
    #pragma unroll
    for (int off = 32; off > 0; off >>= 1)
        m = fmaxf(m, __shfl_down(m, off, 64));
    __shared__ float red[4];
    int lane = threadIdx.x & 63, wv = threadIdx.x >> 6;
    if (lane == 0) red[wv] = m;
    __syncthreads();
    if (threadIdx.x == 0) {
        m = fmaxf(fmaxf(red[0], red[1]), fmaxf(red[2], red[3]));
        atomicMax(ob, __float_as_uint(m));  // valid: all values non-negative
    }
}

__global__ void k_scales(const unsigned* __restrict__ bits, float* __restrict__ sc) {
    float s[2];
    for (int i = 0; i < 2; ++i) {
        float m = __uint_as_float(bits[i]);
        int ex = 0;
        if (m > 0.0f) {
            int e;
            float f = frexpf(m, &e);         // m = f * 2^e, f in [0.5,1)
            ex = (f == 0.5f) ? (e - 1) : e;  // exact ceil(log2(m))
        }
        s[i] = ldexpf(1.0f, 7 - ex);
    }
    sc[0] = s[0]; sc[1] = s[1];
    sc[2] = 1.0f / (s[0] * s[1]);            // exact (powers of two)
}

// fused quantize: round-half-even (== jnp.round), clip after round
__global__ void k_quant(const float4* __restrict__ x, int* __restrict__ qx, int n4x, int nbx,
                        const float4* __restrict__ w, int* __restrict__ qw, int n4w, int nbw,
                        const float* __restrict__ scp) {
    const float4* in; int* out;
    int n4, b, nb; float s;
    if ((int)blockIdx.x < nbx) { in = x; out = qx; n4 = n4x; b = blockIdx.x; nb = nbx; s = scp[0]; }
    else { in = w; out = qw; n4 = n4w; b = blockIdx.x - nbx; nb = nbw; s = scp[1]; }
    int stride = nb * blockDim.x;
    for (int i = b * blockDim.x + threadIdx.x; i < n4; i += stride) {
        float4 v = in[i];
        int qa = (int)rintf(v.x * s); qa = qa > 127 ? 127 : (qa < -127 ? -127 : qa);
        int qb = (int)rintf(v.y * s); qb = qb > 127 ? 127 : (qb < -127 ? -127 : qb);
        int qc = (int)rintf(v.z * s); qc = qc > 127 ? 127 : (qc < -127 ? -127 : qc);
        int qd = (int)rintf(v.w * s); qd = qd > 127 ? 127 : (qd < -127 ? -127 : qd);
        out[i] = (qa & 0xff) | ((qb & 0xff) << 8) | ((qc & 0xff) << 16) | (qd << 24);
    }
}

// ---------------------------------------------------------------------------
// int8 NT GEMM, 128x128 tile, BK=64, double-buffered LDS, one barrier/iter.
// LDS layout (per matrix, per buffer): chunk-major [4][128][16B]:
//   byte offset = (k_chunk*128 + row)*16  -> fragment reads are conflict-free
//   (lane l hits banks 4*(l&31)..+3; every bank exactly 8 words = minimum).
// Staging: thread t loads the global chunk that belongs at LDS linear chunk
//   L (row = L&127, k_chunk = L>>7), dest = base + L*16 (wave-contiguous).
// Fragments (verified exact in round 1):
//   A/B: lane holds [m|n = lane&31][k = (lane>>5)*16 + j]
//   C/D: col = lane&31, row = (r&3) + 8*(r>>2) + 4*(lane>>5)
// ---------------------------------------------------------------------------
__global__ __launch_bounds__(256, 3) void k_gemm(const signed char* __restrict__ A,
                                                 const signed char* __restrict__ B,
                                                 float* __restrict__ out,
                                                 const float* __restrict__ scp) {
    __shared__ __align__(16) signed char sm[2][2][8192];  // [buf][A/B][bytes]
    const int tid  = threadIdx.x;
    const int lane = tid & 63;
    const int wave = tid >> 6;
    const int wm   = wave & 1;
    const int wn   = wave >> 1;
    const int m0   = blockIdx.y * 128;
    const int n0   = blockIdx.x * 128;
    const int l31  = lane & 31;
    const int lhi  = lane >> 5;

    v16i acc[2][2];
    #pragma unroll
    for (int a = 0; a < 2; ++a)
        #pragma unroll
        for (int b = 0; b < 2; ++b)
            #pragma unroll
            for (int i = 0; i < 16; ++i) acc[a][b][i] = 0;

    const int L0 = tid, L1 = tid + 256;
    const signed char* gA0 = A + (size_t)(m0 + (L0 & 127)) * 1024 + (L0 >> 7) * 16;
    const signed char* gA1 = A + (size_t)(m0 + (L1 & 127)) * 1024 + (L1 >> 7) * 16;
    const signed char* gB0 = B + (size_t)(n0 + (L0 & 127)) * 1024 + (L0 >> 7) * 16;
    const signed char* gB1 = B + (size_t)(n0 + (L1 & 127)) * 1024 + (L1 >> 7) * 16;

    // prologue: stage tile 0 into buf 0
    async_load16(gA0, &sm[0][0][L0 * 16]);
    async_load16(gA1, &sm[0][0][L1 * 16]);
    async_load16(gB0, &sm[0][1][L0 * 16]);
    async_load16(gB1, &sm[0][1][L1 * 16]);

    for (int it = 0; it < 16; ++it) {
        __syncthreads();  // drains buf[it&1] loads (and last iter's prefetch)
        if (it < 15) {
            const int k0 = (it + 1) * 64;
            const int nb = (it + 1) & 1;
            async_load16(gA0 + k0, &sm[nb][0][L0 * 16]);
            async_load16(gA1 + k0, &sm[nb][0][L1 * 16]);
            async_load16(gB0 + k0, &sm[nb][1][L0 * 16]);
            async_load16(gB1 + k0, &sm[nb][1][L1 * 16]);
        }
        const signed char* As = sm[it & 1][0];
        const signed char* Bs = sm[it & 1][1];
        #pragma unroll
        for (int kc = 0; kc < 2; ++kc) {
            const int c = kc * 2 + lhi;  // k-chunk index
            v4i a0 = *(const v4i*)(As + (c * 128 + wm * 64 +      l31) * 16);
            v4i a1 = *(const v4i*)(As + (c * 128 + wm * 64 + 32 + l31) * 16);
            v4i b0 = *(const v4i*)(Bs + (c * 128 + wn * 64 +      l31) * 16);
            v4i b1 = *(const v4i*)(Bs + (c * 128 + wn * 64 + 32 + l31) * 16);
            acc[0][0] = __builtin_amdgcn_mfma_i32_32x32x32_i8(a0, b0, acc[0][0], 0, 0, 0);
            acc[0][1] = __builtin_amdgcn_mfma_i32_32x32x32_i8(a0, b1, acc[0][1], 0, 0, 0);
            acc[1][0] = __builtin_amdgcn_mfma_i32_32x32x32_i8(a1, b0, acc[1][0], 0, 0, 0);
            acc[1][1] = __builtin_amdgcn_mfma_i32_32x32x32_i8(a1, b1, acc[1][1], 0, 0, 0);
        }
    }

    const float inv = scp[2];
    #pragma unroll
    for (int tm = 0; tm < 2; ++tm)
        #pragma unroll
        for (int tn = 0; tn < 2; ++tn)
            #pragma unroll
            for (int r = 0; r < 16; ++r) {
                int row = m0 + wm * 64 + tm * 32 + (r & 3) + 8 * (r >> 2) + 4 * lhi;
                int col = n0 + wn * 64 + tn * 32 + l31;
                out[(size_t)row * 1024 + col] = (float)acc[tm][tn][r] * inv;
            }
}

// ---------------------------------------------------------------------------
extern "C" void kernel_launch(void* const* d_in, const int* in_sizes, int n_in,
                              void* d_out, int out_size, void* d_ws, size_t ws_size,
                              hipStream_t stream) {
    const float* x = (const float*)d_in[0];   // [65536,1024] fp32
    const float* w = (const float*)d_in[1];   // [1024,1024] fp32
    float* out = (float*)d_out;               // [65536,1024] fp32

    const int NX = 65536 * 1024;
    const int NW = 1024 * 1024;

    char* ws = (char*)d_ws;
    unsigned* bits = (unsigned*)ws;
    float* sc = (float*)(ws + 8);
    signed char* qx = (signed char*)(ws + 256);
    signed char* qw = qx + (size_t)NX;

    const int NBX_A = 8192, NBW_A = 128;      // absmax blocks (x, w)
    const int NBX_Q = 8192, NBW_Q = 128;      // quant blocks (x, w)

    k_init<<<1, 64, 0, stream>>>(bits);
    k_absmax<<<NBX_A + NBW_A, 256, 0, stream>>>(
        (const float4*)x, NX / 4, NBX_A, (const float4*)w, NW / 4, NBW_A, bits);
    k_scales<<<1, 1, 0, stream>>>(bits, sc);
    k_quant<<<NBX_Q + NBW_Q, 256, 0, stream>>>(
        (const float4*)x, (int*)qx, NX / 4, NBX_Q,
        (const float4*)w, (int*)qw, NW / 4, NBW_Q, sc);

    dim3 grid(1024 / 128, 65536 / 128);       // (8, 512)
    k_gemm<<<grid, 256, 0, stream>>>(qx, qw, out, sc);
}

// Round 3
// 639.143 us; speedup vs baseline: 1.0307x; 1.0307x over previous
//
#include <hip/hip_runtime.h>
#include <stdint.h>

typedef int v4i  __attribute__((ext_vector_type(4)));
typedef int v16i __attribute__((ext_vector_type(16)));

// async global->LDS, 16 B per lane; LDS dest = wave-uniform base + lane*16.
__device__ __forceinline__ void async_load16(const void* g, void* l) {
    auto gp = (const __attribute__((address_space(1))) unsigned int*)(uintptr_t)g;
    auto lp = (__attribute__((address_space(3))) unsigned int*)(unsigned int)(uintptr_t)l;
    __builtin_amdgcn_global_load_lds(gp, lp, 16, 0, 0);
}

// ---------------------------------------------------------------------------
// absmax: per-block partial maxes (no init kernel, no atomics).
// blocks [0,nbx) -> x, [nbx,grid) -> w. part[blockIdx.x] = block max.
// ---------------------------------------------------------------------------
__global__ void k_absmax(const float4* __restrict__ x, int n4x, int nbx,
                         const float4* __restrict__ w, int n4w,
                         float* __restrict__ part) {
    const float4* in;
    int n4, b, nb;
    if ((int)blockIdx.x < nbx) { in = x; n4 = n4x; b = blockIdx.x; nb = nbx; }
    else { in = w; n4 = n4w; b = blockIdx.x - nbx; nb = gridDim.x - nbx; }
    float m0 = 0.f, m1 = 0.f;
    int stride = nb * blockDim.x * 2;
    for (int i = b * blockDim.x * 2 + threadIdx.x; i < n4; i += stride) {
        float4 v = in[i];
        m0 = fmaxf(m0, fmaxf(fmaxf(fabsf(v.x), fabsf(v.y)),
                             fmaxf(fabsf(v.z), fabsf(v.w))));
        int j = i + blockDim.x;
        if (j < n4) {
            float4 u = in[j];
            m1 = fmaxf(m1, fmaxf(fmaxf(fabsf(u.x), fabsf(u.y)),
                                 fmaxf(fabsf(u.z), fabsf(u.w))));
        }
    }
    float m = fmaxf(m0, m1);
    #pragma unroll
    for (int off = 32; off > 0; off >>= 1)
        m = fmaxf(m, __shfl_down(m, off, 64));
    __shared__ float red[4];
    int lane = threadIdx.x & 63, wv = threadIdx.x >> 6;
    if (lane == 0) red[wv] = m;
    __syncthreads();
    if (threadIdx.x == 0)
        part[blockIdx.x] = fmaxf(fmaxf(red[0], red[1]), fmaxf(red[2], red[3]));
}

// reduce partials, compute exact power-of-two scales
__global__ void k_scales(const float* __restrict__ part, int nbx, int nbw,
                         float* __restrict__ sc) {
    float mx = 0.f, mw = 0.f;
    for (int i = threadIdx.x; i < nbx; i += 256) mx = fmaxf(mx, part[i]);
    for (int i = threadIdx.x; i < nbw; i += 256) mw = fmaxf(mw, part[nbx + i]);
    #pragma unroll
    for (int off = 32; off > 0; off >>= 1) {
        mx = fmaxf(mx, __shfl_down(mx, off, 64));
        mw = fmaxf(mw, __shfl_down(mw, off, 64));
    }
    __shared__ float rx[4], rw[4];
    int lane = threadIdx.x & 63, wv = threadIdx.x >> 6;
    if (lane == 0) { rx[wv] = mx; rw[wv] = mw; }
    __syncthreads();
    if (threadIdx.x == 0) {
        float m[2] = { fmaxf(fmaxf(rx[0], rx[1]), fmaxf(rx[2], rx[3])),
                       fmaxf(fmaxf(rw[0], rw[1]), fmaxf(rw[2], rw[3])) };
        float s[2];
        for (int i = 0; i < 2; ++i) {
            int ex = 0;
            if (m[i] > 0.0f) {
                int e;
                float f = frexpf(m[i], &e);       // m = f * 2^e, f in [0.5,1)
                ex = (f == 0.5f) ? (e - 1) : e;   // exact ceil(log2(m))
            }
            s[i] = ldexpf(1.0f, 7 - ex);
        }
        sc[0] = s[0]; sc[1] = s[1];
        sc[2] = 1.0f / (s[0] * s[1]);             // powers of two: exact
    }
}

// fused quantize: round-half-even (== jnp.round), clip after round
__global__ void k_quant(const float4* __restrict__ x, int* __restrict__ qx, int n4x, int nbx,
                        const float4* __restrict__ w, int* __restrict__ qw, int n4w,
                        const float* __restrict__ scp) {
    const float4* in; int* out;
    int n4, b, nb; float s;
    if ((int)blockIdx.x < nbx) { in = x; out = qx; n4 = n4x; b = blockIdx.x; nb = nbx; s = scp[0]; }
    else { in = w; out = qw; n4 = n4w; b = blockIdx.x - nbx; nb = gridDim.x - nbx; s = scp[1]; }
    int stride = nb * blockDim.x;
    for (int i = b * blockDim.x + threadIdx.x; i < n4; i += stride) {
        float4 v = in[i];
        int qa = (int)rintf(v.x * s); qa = qa > 127 ? 127 : (qa < -127 ? -127 : qa);
        int qb = (int)rintf(v.y * s); qb = qb > 127 ? 127 : (qb < -127 ? -127 : qb);
        int qc = (int)rintf(v.z * s); qc = qc > 127 ? 127 : (qc < -127 ? -127 : qc);
        int qd = (int)rintf(v.w * s); qd = qd > 127 ? 127 : (qd < -127 ? -127 : qd);
        out[i] = (qa & 0xff) | ((qb & 0xff) << 8) | ((qc & 0xff) << 16) | (qd << 24);
    }
}

// ---------------------------------------------------------------------------
// int8 NT GEMM, 128x128 tile, BK=64. 3 LDS buffers, prefetch distance 2,
// raw s_barrier + manual s_waitcnt vmcnt(N) — no vmcnt(0) drain anywhere in
// the K-loop (the __syncthreads drain was the round-2 regression).
// Per iter:
//   s_barrier                 (#1: everyone retired compute(it-1) -> slot
//                              (it+2)%3 == (it-1)%3 is safe to overwrite)
//   stage tile it+2           (4 async loads/thread)
//   s_waitcnt vmcnt(8)        (own tile-it loads done; 8 newer stay in flight)
//   s_barrier                 (#2: ALL threads' tile-it loads done)
//   compute tile it
// XCD swizzle: XCD g = b&7 owns m-strips [g*64,g*64+64); the 8 n-tiles of a
// strip run consecutively on one XCD -> A stays L2-hot.
// LDS chunk-major layout (conflict-free): byte = (k_chunk*128 + row)*16.
// Fragments (verified exact rounds 1-2):
//   A/B: lane holds [m|n = lane&31][k = (lane>>5)*16 + j]
//   C/D: col = lane&31, row = (r&3) + 8*(r>>2) + 4*(lane>>5)
// ---------------------------------------------------------------------------
__global__ __launch_bounds__(256, 3) void k_gemm(const signed char* __restrict__ A,
                                                 const signed char* __restrict__ B,
                                                 float* __restrict__ out,
                                                 const float* __restrict__ scp) {
    __shared__ __align__(16) signed char sm[3][2][8192];  // [buf][A/B][bytes]
    const int tid  = threadIdx.x;
    const int lane = tid & 63;
    const int wave = tid >> 6;
    const int wm   = wave & 1;
    const int wn   = wave >> 1;
    const int bl   = blockIdx.x;
    const int g    = bl & 7;            // XCD id (round-robin heuristic)
    const int j    = bl >> 3;
    const int n0   = (j & 7) * 128;
    const int m0   = (g * 64 + (j >> 3)) * 128;
    const int l31  = lane & 31;
    const int lhi  = lane >> 5;

    v16i acc[2][2];
    #pragma unroll
    for (int a = 0; a < 2; ++a)
        #pragma unroll
        for (int b = 0; b < 2; ++b)
            #pragma unroll
            for (int i = 0; i < 16; ++i) acc[a][b][i] = 0;

    const int L0 = tid, L1 = tid + 256;
    const signed char* gA0 = A + (size_t)(m0 + (L0 & 127)) * 1024 + (L0 >> 7) * 16;
    const signed char* gA1 = A + (size_t)(m0 + (L1 & 127)) * 1024 + (L1 >> 7) * 16;
    const signed char* gB0 = B + (size_t)(n0 + (L0 & 127)) * 1024 + (L0 >> 7) * 16;
    const signed char* gB1 = B + (size_t)(n0 + (L1 & 127)) * 1024 + (L1 >> 7) * 16;
    const int o0 = L0 * 16, o1 = L1 * 16;

    // prologue: stage tiles 0 and 1 into slots 0,1 (8 loads outstanding)
    async_load16(gA0,      &sm[0][0][o0]);
    async_load16(gA1,      &sm[0][0][o1]);
    async_load16(gB0,      &sm[0][1][o0]);
    async_load16(gB1,      &sm[0][1][o1]);
    async_load16(gA0 + 64, &sm[1][0][o0]);
    async_load16(gA1 + 64, &sm[1][0][o1]);
    async_load16(gB0 + 64, &sm[1][1][o0]);
    async_load16(gB1 + 64, &sm[1][1][o1]);

    for (int it = 0; it < 16; ++it) {
        __builtin_amdgcn_s_barrier();            // retire compute(it-1), no drain
        if (it < 14) {
            const int k0 = (it + 2) * 64;
            const int s  = (it + 2) % 3;
            async_load16(gA0 + k0, &sm[s][0][o0]);
            async_load16(gA1 + k0, &sm[s][0][o1]);
            async_load16(gB0 + k0, &sm[s][1][o0]);
            async_load16(gB1 + k0, &sm[s][1][o1]);
            asm volatile("s_waitcnt vmcnt(8)" ::: "memory");   // tile(it) done
        } else if (it == 14) {
            asm volatile("s_waitcnt vmcnt(4)" ::: "memory");
        } else {
            asm volatile("s_waitcnt vmcnt(0)" ::: "memory");
        }
        __builtin_amdgcn_s_barrier();            // all threads' tile(it) ready
        const signed char* As = &sm[it % 3][0][0];
        const signed char* Bs = &sm[it % 3][1][0];
        #pragma unroll
        for (int kc = 0; kc < 2; ++kc) {
            const int c = kc * 2 + lhi;  // k-chunk index
            v4i a0 = *(const v4i*)(As + (c * 128 + wm * 64 +      l31) * 16);
            v4i a1 = *(const v4i*)(As + (c * 128 + wm * 64 + 32 + l31) * 16);
            v4i b0 = *(const v4i*)(Bs + (c * 128 + wn * 64 +      l31) * 16);
            v4i b1 = *(const v4i*)(Bs + (c * 128 + wn * 64 + 32 + l31) * 16);
            acc[0][0] = __builtin_amdgcn_mfma_i32_32x32x32_i8(a0, b0, acc[0][0], 0, 0, 0);
            acc[0][1] = __builtin_amdgcn_mfma_i32_32x32x32_i8(a0, b1, acc[0][1], 0, 0, 0);
            acc[1][0] = __builtin_amdgcn_mfma_i32_32x32x32_i8(a1, b0, acc[1][0], 0, 0, 0);
            acc[1][1] = __builtin_amdgcn_mfma_i32_32x32x32_i8(a1, b1, acc[1][1], 0, 0, 0);
        }
    }

    const float inv = scp[2];
    #pragma unroll
    for (int tm = 0; tm < 2; ++tm)
        #pragma unroll
        for (int tn = 0; tn < 2; ++tn)
            #pragma unroll
            for (int r = 0; r < 16; ++r) {
                int row = m0 + wm * 64 + tm * 32 + (r & 3) + 8 * (r >> 2) + 4 * lhi;
                int col = n0 + wn * 64 + tn * 32 + l31;
                out[(size_t)row * 1024 + col] = (float)acc[tm][tn][r] * inv;
            }
}

// ---------------------------------------------------------------------------
extern "C" void kernel_launch(void* const* d_in, const int* in_sizes, int n_in,
                              void* d_out, int out_size, void* d_ws, size_t ws_size,
                              hipStream_t stream) {
    const float* x = (const float*)d_in[0];   // [65536,1024] fp32
    const float* w = (const float*)d_in[1];   // [1024,1024] fp32
    float* out = (float*)d_out;               // [65536,1024] fp32

    const int NX = 65536 * 1024;
    const int NW = 1024 * 1024;

    char* ws = (char*)d_ws;
    float* sc   = (float*)ws;                     // 3 floats
    float* part = (float*)(ws + 256);             // 8320 partial maxes
    signed char* qx = (signed char*)(ws + 65536); // 64 MB
    signed char* qw = qx + (size_t)NX;            // 1 MB

    const int NBX = 8192, NBW = 128;

    k_absmax<<<NBX + NBW, 256, 0, stream>>>(
        (const float4*)x, NX / 4, NBX, (const float4*)w, NW / 4, part);
    k_scales<<<1, 256, 0, stream>>>(part, NBX, NBW, sc);
    k_quant<<<NBX + NBW, 256, 0, stream>>>(
        (const float4*)x, (int*)qx, NX / 4, NBX,
        (const float4*)w, (int*)qw, NW / 4, sc);
    k_gemm<<<4096, 256, 0, stream>>>(qx, qw, out, sc);
}